// Round 1
// 869.770 us; speedup vs baseline: 1.0757x; 1.0757x over previous
//
#include <hip/hip_runtime.h>
#include <cstdint>

#define NTOK 8192
#define CDIM 1024
#define HDIM 1408
#define HSDIM 2816
#define NEXP 8

typedef __attribute__((ext_vector_type(8))) short s8v;
typedef __attribute__((ext_vector_type(4))) float f4v;
typedef __attribute__((ext_vector_type(8))) unsigned short u16x8;

__device__ __forceinline__ unsigned short f2bf(float f) {
    unsigned int u = __float_as_uint(f);
    unsigned int r = (u + 0x7fffu + ((u >> 16) & 1u)) >> 16;  // RNE
    return (unsigned short)r;
}
__device__ __forceinline__ float bf2f(unsigned short u) {
    return __uint_as_float(((unsigned int)u) << 16);
}

// Direct global->LDS 16B async copy. LDS dest must be wave-uniform-base +
// lane*16 (our staging layout is exactly linear-in-tid, swizzle is carried
// on the GLOBAL source address per m173).
__device__ __forceinline__ void gld_lds16(const unsigned short* g, unsigned short* l) {
    __builtin_amdgcn_global_load_lds(
        (const __attribute__((address_space(1))) void*)g,
        (__attribute__((address_space(3))) void*)l, 16, 0, 0);
}

// ---------------- conversion kernels ----------------

__global__ void cvt_bf16_kernel(const float4* __restrict__ in, ushort4* __restrict__ out, int n4) {
    int i = blockIdx.x * blockDim.x + threadIdx.x;
    if (i < n4) {
        float4 v = in[i];
        ushort4 o;
        o.x = f2bf(v.x); o.y = f2bf(v.y); o.z = f2bf(v.z); o.w = f2bf(v.w);
        out[i] = o;
    }
}

// 64x64 LDS-staged transpose+cvt: fp32 [z][R][Cc] -> bf16 [z][Cc][R].
__global__ __launch_bounds__(256) void transpose_cvt_kernel(
    const float* __restrict__ in0, const float* __restrict__ in1,
    unsigned short* __restrict__ out0, unsigned short* __restrict__ out1,
    int R, int Cc, int zsplit) {
    __shared__ float T[64][68];
    int z = blockIdx.z;
    const float* in = (z < zsplit) ? in0 : in1;
    unsigned short* out = (z < zsplit) ? out0 : out1;
    int zz = (z < zsplit) ? z : z - zsplit;
    const size_t bs = (size_t)R * Cc;
    in += zz * bs; out += zz * bs;

    const int t = threadIdx.x;
    const int r0 = blockIdx.y * 64, c0 = blockIdx.x * 64;

    {
        const int rl = t >> 2, cq = t & 3;
        const float* src = in + (size_t)(r0 + rl) * Cc + c0;
#pragma unroll
        for (int i = 0; i < 4; i++) {
            float4 v = *(const float4*)(src + (cq + 4 * i) * 4);
            *(float4*)&T[rl][(cq + 4 * i) * 4] = v;
        }
    }
    __syncthreads();
    {
        const int cl = t >> 2, rq = t & 3;
        unsigned short* dst = out + (size_t)(c0 + cl) * R + r0 + rq * 16;
        u16x8 lo, hi;
#pragma unroll
        for (int j = 0; j < 8; j++) lo[j] = f2bf(T[rq * 16 + j][cl]);
#pragma unroll
        for (int j = 0; j < 8; j++) hi[j] = f2bf(T[rq * 16 + 8 + j][cl]);
        *(u16x8*)dst = lo;
        *(u16x8*)(dst + 8) = hi;
    }
}

// ---------------- router ----------------
__global__ void router_kernel(const float* __restrict__ x, const float* __restrict__ Wg,
                              int* __restrict__ idxK, float* __restrict__ probK,
                              int* __restrict__ meta) {
    int t = blockIdx.x;
    int lane = threadIdx.x;
    const float* xr = x + (size_t)t * CDIM;
    float acc[NEXP];
#pragma unroll
    for (int e = 0; e < NEXP; e++) acc[e] = 0.f;
    for (int c = lane; c < CDIM; c += 64) {
        float xv = xr[c];
        const float* wr = Wg + c * NEXP;
#pragma unroll
        for (int e = 0; e < NEXP; e++) acc[e] += xv * wr[e];
    }
#pragma unroll
    for (int e = 0; e < NEXP; e++)
        for (int off = 32; off > 0; off >>= 1)
            acc[e] += __shfl_down(acc[e], off, 64);
    if (lane == 0) {
        int b0 = 0; float v0 = acc[0];
#pragma unroll
        for (int e = 1; e < NEXP; e++) if (acc[e] > v0) { v0 = acc[e]; b0 = e; }
        int b1 = -1; float v1 = -1e30f;
#pragma unroll
        for (int e = 0; e < NEXP; e++) if (e != b0 && acc[e] > v1) { v1 = acc[e]; b1 = e; }
        float p0 = 1.f / (1.f + __expf(v1 - v0));
        idxK[2 * t] = b0; idxK[2 * t + 1] = b1;
        probK[2 * t] = p0; probK[2 * t + 1] = 1.f - p0;
        atomicAdd(&meta[b0], 1);
        atomicAdd(&meta[b1], 1);
    }
}

// meta: [0..7] counts, [8..15] offsets, [16..23] cursor
__global__ void offsets_kernel(int* meta) {
    int s = 0;
    for (int e = 0; e < NEXP; e++) { meta[8 + e] = s; meta[16 + e] = s; s += meta[e]; }
}

__global__ void fill_kernel(const int* __restrict__ idxK, const float* __restrict__ probK,
                            int* __restrict__ meta, int* __restrict__ rowT, float* __restrict__ rowW,
                            int* __restrict__ tokSlot) {
    int t = blockIdx.x * 256 + threadIdx.x;
    if (t >= NTOK) return;
#pragma unroll
    for (int k = 0; k < 2; k++) {
        int e = idxK[2 * t + k];
        int p = atomicAdd(&meta[16 + e], 1);
        rowT[p] = t;
        rowW[p] = probK[2 * t + k];
        tokSlot[2 * t + k] = p;
    }
}

// ---------------- merged fused gate GEMM: H = silu(A@W1) * (A@W2) ----------------
// 1D grid, XCD-pinned: ids [0,3520): experts, id%8==z; ids [3520,6336): shared.
// BM=128, BN=64, BK=32. global_load_lds staging (m97 structure): LDS dest is
// linear in tid, bank-swizzle carried on the global source column (co).
__global__ __launch_bounds__(256) void gemm12_kernel(
    const unsigned short* __restrict__ xb,
    const unsigned short* __restrict__ w1, const unsigned short* __restrict__ w2,
    const unsigned short* __restrict__ ws1, const unsigned short* __restrict__ ws2,
    unsigned short* __restrict__ hE, unsigned short* __restrict__ hS,
    const int* __restrict__ rowT, const int* __restrict__ meta) {
    const int id = blockIdx.x;
    int z, m0, n0; bool SH;
    if (id < 3520) { SH = false; z = id & 7; int q = id >> 3; m0 = (q % 20) * 128; n0 = (q / 20) * 64; }
    else           { SH = true;  z = 8; int q = id - 3520; m0 = (q & 63) * 128; n0 = (q >> 6) * 64; }
    const int M = SH ? NTOK : meta[z];
    const int base = SH ? 0 : meta[8 + z];
    if (m0 >= M) return;

    const unsigned short* B1 = SH ? ws1 : w1 + (size_t)z * HDIM * CDIM;
    const unsigned short* B2 = SH ? ws2 : w2 + (size_t)z * HDIM * CDIM;

    __shared__ unsigned short L[16384];  // 32 KB

    const int tid = threadIdx.x;
    const int srow = tid >> 2;
    const int key = (tid >> 3) & 3;
    const int co = ((tid & 3) ^ key) << 3;

    int am0 = m0 + srow;       am0 = am0 < M ? am0 : M - 1;
    int am1 = m0 + 64 + srow;  am1 = am1 < M ? am1 : M - 1;
    long ar0 = SH ? am0 : rowT[base + am0];
    long ar1 = SH ? am1 : rowT[base + am1];
    const unsigned short* a0p = xb + (size_t)ar0 * CDIM + co;
    const unsigned short* a1p = xb + (size_t)ar1 * CDIM + co;
    const unsigned short* b1p = B1 + (size_t)(n0 + srow) * CDIM + co;
    const unsigned short* b2p = B2 + (size_t)(n0 + srow) * CDIM + co;

    const int w = tid >> 6, lane = tid & 63;
    const int wm = (w >> 1) * 64, wn = (w & 1) * 32;
    const int quad = lane >> 4, l15 = lane & 15;
    const int rcx = (quad ^ ((l15 >> 1) & 3)) << 3;

    f4v acc1[4][2], acc2[4][2];
#pragma unroll
    for (int i = 0; i < 4; i++)
#pragma unroll
        for (int j = 0; j < 2; j++) {
            f4v zz = {0.f, 0.f, 0.f, 0.f};
            acc1[i][j] = zz; acc2[i][j] = zz;
        }

    // async staging: 4x global_load_lds(16B) per thread per K-step
#define STAGE12(b, k0) do { \
        gld_lds16(a0p + (k0), L + (b) * 4096 + tid * 8); \
        gld_lds16(a1p + (k0), L + (b) * 4096 + 2048 + tid * 8); \
        gld_lds16(b1p + (k0), L + 8192 + (b) * 2048 + tid * 8); \
        gld_lds16(b2p + (k0), L + 12288 + (b) * 2048 + tid * 8); } while (0)

    auto compute = [&](int b) {
        const unsigned short* Ab = L + b * 4096;
        const unsigned short* B1b = L + 8192 + b * 2048;
        const unsigned short* B2b = L + 12288 + b * 2048;
        s8v af[4], bf1[2], bf2[2];
#pragma unroll
        for (int mt = 0; mt < 4; mt++)
            af[mt] = *(const s8v*)(Ab + (wm + mt * 16 + l15) * 32 + rcx);
#pragma unroll
        for (int nt = 0; nt < 2; nt++) {
            bf1[nt] = *(const s8v*)(B1b + (wn + nt * 16 + l15) * 32 + rcx);
            bf2[nt] = *(const s8v*)(B2b + (wn + nt * 16 + l15) * 32 + rcx);
        }
#pragma unroll
        for (int mt = 0; mt < 4; mt++)
#pragma unroll
            for (int nt = 0; nt < 2; nt++) {
                acc1[mt][nt] = __builtin_amdgcn_mfma_f32_16x16x32_bf16(af[mt], bf1[nt], acc1[mt][nt], 0, 0, 0);
                acc2[mt][nt] = __builtin_amdgcn_mfma_f32_16x16x32_bf16(af[mt], bf2[nt], acc2[mt][nt], 0, 0, 0);
            }
    };

    const int NS = CDIM / 32;
    STAGE12(0, 0);
    __syncthreads();
#pragma unroll 1
    for (int ks = 0; ks < NS; ks++) {
        if (ks + 1 < NS) STAGE12((ks + 1) & 1, (ks + 1) * 32);
        compute(ks & 1);
        __syncthreads();
    }
#undef STAGE12

#pragma unroll
    for (int mt = 0; mt < 4; mt++) {
#pragma unroll
        for (int r = 0; r < 4; r++) {
            int gm = m0 + wm + mt * 16 + quad * 4 + r;
            if (gm < M) {
                unsigned short* hrow = SH ? hS + (size_t)gm * HSDIM
                                          : hE + (size_t)(base + gm) * HDIM;
#pragma unroll
                for (int nt = 0; nt < 2; nt++) {
                    float z1 = acc1[mt][nt][r];
                    float z2 = acc2[mt][nt][r];
                    float hv = (z1 / (1.f + __expf(-z1))) * z2;
                    hrow[n0 + wn + nt * 16 + l15] = f2bf(hv);
                }
            }
        }
    }
}

// ---------------- merged down-proj GEMM ----------------
// z<8: expert -> PLAIN bf16 stores to pE[slot][c] (no atomics).
// z==8: shared -> plain fp32 stores directly to Out (covers every element).
__global__ __launch_bounds__(256) void gemm3_kernel(
    const unsigned short* __restrict__ hE, const unsigned short* __restrict__ hS,
    const unsigned short* __restrict__ w3, const unsigned short* __restrict__ ws3,
    float* __restrict__ Out, unsigned short* __restrict__ pE,
    const int* __restrict__ rowT, const float* __restrict__ rowW, const int* __restrict__ meta) {
    const int id = blockIdx.x;
    int z, m0, n0; bool SH;
    if (id < 1280) { SH = false; z = id & 7; int q = id >> 3; m0 = (q % 20) * 128; n0 = (q / 20) * 128; }
    else           { SH = true;  z = 8; int q = id - 1280; m0 = (q & 63) * 128; n0 = (q >> 6) * 128; }
    const int M = SH ? NTOK : meta[z];
    const int base = SH ? 0 : meta[8 + z];
    if (m0 >= M) return;
    const int K = SH ? HSDIM : HDIM;
    const unsigned short* A = SH ? hS : hE;
    const unsigned short* B = SH ? ws3 : w3 + (size_t)z * CDIM * HDIM;

    __shared__ unsigned short L[16384];

    const int tid = threadIdx.x;
    const int srow = tid >> 2;
    const int key = (tid >> 3) & 3;
    const int co = ((tid & 3) ^ key) << 3;

    int am0 = m0 + srow;       am0 = am0 < M ? am0 : M - 1;
    int am1 = m0 + 64 + srow;  am1 = am1 < M ? am1 : M - 1;
    const unsigned short* a0p = A + (size_t)(base + am0) * K + co;
    const unsigned short* a1p = A + (size_t)(base + am1) * K + co;
    const unsigned short* b0p = B + (size_t)(n0 + srow) * K + co;
    const unsigned short* b1p = B + (size_t)(n0 + 64 + srow) * K + co;

    const int w = tid >> 6, lane = tid & 63;
    const int wm = (w >> 1) * 64, wn = (w & 1) * 64;
    const int quad = lane >> 4, l15 = lane & 15;
    const int rcx = (quad ^ ((l15 >> 1) & 3)) << 3;

    f4v acc[4][4];
#pragma unroll
    for (int i = 0; i < 4; i++)
#pragma unroll
        for (int j = 0; j < 4; j++) {
            f4v zz = {0.f, 0.f, 0.f, 0.f};
            acc[i][j] = zz;
        }

#define STAGE3(b, k0) do { \
        gld_lds16(a0p + (k0), L + (b) * 4096 + tid * 8); \
        gld_lds16(a1p + (k0), L + (b) * 4096 + 2048 + tid * 8); \
        gld_lds16(b0p + (k0), L + 8192 + (b) * 4096 + tid * 8); \
        gld_lds16(b1p + (k0), L + 8192 + (b) * 4096 + 2048 + tid * 8); } while (0)

    auto compute = [&](int b) {
        const unsigned short* Ab = L + b * 4096;
        const unsigned short* Bb = L + 8192 + b * 4096;
        s8v af[4], bf[4];
#pragma unroll
        for (int mt = 0; mt < 4; mt++)
            af[mt] = *(const s8v*)(Ab + (wm + mt * 16 + l15) * 32 + rcx);
#pragma unroll
        for (int nt = 0; nt < 4; nt++)
            bf[nt] = *(const s8v*)(Bb + (wn + nt * 16 + l15) * 32 + rcx);
#pragma unroll
        for (int mt = 0; mt < 4; mt++)
#pragma unroll
            for (int nt = 0; nt < 4; nt++)
                acc[mt][nt] = __builtin_amdgcn_mfma_f32_16x16x32_bf16(af[mt], bf[nt], acc[mt][nt], 0, 0, 0);
    };

    const int NS = K / 32;
    STAGE3(0, 0);
    __syncthreads();
#pragma unroll 1
    for (int ks = 0; ks < NS; ks++) {
        if (ks + 1 < NS) STAGE3((ks + 1) & 1, (ks + 1) * 32);
        compute(ks & 1);
        __syncthreads();
    }
#undef STAGE3

#pragma unroll
    for (int mt = 0; mt < 4; mt++) {
#pragma unroll
        for (int r = 0; r < 4; r++) {
            int gm = m0 + wm + mt * 16 + quad * 4 + r;
            if (gm < M) {
                if (SH) {
                    size_t o = (size_t)gm * CDIM + n0 + wn + l15;
#pragma unroll
                    for (int nt = 0; nt < 4; nt++)
                        Out[o + nt * 16] = acc[mt][nt][r];
                } else {
                    size_t o = (size_t)(base + gm) * CDIM + n0 + wn + l15;
#pragma unroll
                    for (int nt = 0; nt < 4; nt++)
                        pE[o + nt * 16] = f2bf(acc[mt][nt][r]);
                }
            }
        }
    }
}

// ---------------- combine: out[t] += w0*pE[s0] + w1*pE[s1] ----------------
__global__ __launch_bounds__(256) void combine_kernel(
    float* __restrict__ Out, const unsigned short* __restrict__ pE,
    const int* __restrict__ tokSlot, const float* __restrict__ rowW) {
    const int t = blockIdx.x;
    const int c = threadIdx.x * 4;
    const int s0 = tokSlot[2 * t], s1 = tokSlot[2 * t + 1];
    const float w0 = rowW[s0], w1 = rowW[s1];
    float* op = Out + (size_t)t * CDIM + c;
    float4 o = *(float4*)op;
    ushort4 a = *(const ushort4*)(pE + (size_t)s0 * CDIM + c);
    ushort4 b = *(const ushort4*)(pE + (size_t)s1 * CDIM + c);
    o.x += w0 * bf2f(a.x) + w1 * bf2f(b.x);
    o.y += w0 * bf2f(a.y) + w1 * bf2f(b.y);
    o.z += w0 * bf2f(a.z) + w1 * bf2f(b.z);
    o.w += w0 * bf2f(a.w) + w1 * bf2f(b.w);
    *(float4*)op = o;
}

// ---------------- launch ----------------

extern "C" void kernel_launch(void* const* d_in, const int* in_sizes, int n_in,
                              void* d_out, int out_size, void* d_ws, size_t ws_size,
                              hipStream_t stream) {
    const float* x   = (const float*)d_in[0];
    const float* Wg  = (const float*)d_in[1];
    const float* W1  = (const float*)d_in[2];
    const float* W2  = (const float*)d_in[3];
    const float* W3  = (const float*)d_in[4];
    const float* Ws1 = (const float*)d_in[5];
    const float* Ws2 = (const float*)d_in[6];
    const float* Ws3 = (const float*)d_in[7];
    float* out = (float*)d_out;

    char* p = (char*)d_ws;
    auto carve = [&](size_t bytes) {
        char* r = p;
        p += (bytes + 255) & ~(size_t)255;
        return r;
    };
    unsigned short* xb   = (unsigned short*)carve((size_t)NTOK * CDIM * 2);
    unsigned short* w1t  = (unsigned short*)carve((size_t)NEXP * HDIM * CDIM * 2);
    unsigned short* w2t  = (unsigned short*)carve((size_t)NEXP * HDIM * CDIM * 2);
    unsigned short* w3t  = (unsigned short*)carve((size_t)NEXP * CDIM * HDIM * 2);
    unsigned short* ws1t = (unsigned short*)carve((size_t)HSDIM * CDIM * 2);
    unsigned short* ws2t = (unsigned short*)carve((size_t)HSDIM * CDIM * 2);
    unsigned short* ws3t = (unsigned short*)carve((size_t)CDIM * HSDIM * 2);
    unsigned short* hE   = (unsigned short*)carve((size_t)2 * NTOK * HDIM * 2);
    unsigned short* hS   = (unsigned short*)carve((size_t)NTOK * HSDIM * 2);
    int*   idxK   = (int*)carve((size_t)NTOK * 2 * 4);
    float* probK  = (float*)carve((size_t)NTOK * 2 * 4);
    int*   rowT   = (int*)carve((size_t)2 * NTOK * 4);
    float* rowW   = (float*)carve((size_t)2 * NTOK * 4);
    int*   tokSlot= (int*)carve((size_t)2 * NTOK * 4);
    int*   meta   = (int*)carve(256);

    // expert partials (bf16, 2N x C = 33.5 MB) alias the w1t+w2t region,
    // which is dead after gemm12 completes (stream-ordered before gemm3).
    unsigned short* pE = w1t;

    cvt_bf16_kernel<<<(NTOK * CDIM / 4 + 255) / 256, 256, 0, stream>>>(
        (const float4*)x, (ushort4*)xb, NTOK * CDIM / 4);
    transpose_cvt_kernel<<<dim3(HDIM / 64, CDIM / 64, 16), 256, 0, stream>>>(
        W1, W2, w1t, w2t, CDIM, HDIM, 8);
    transpose_cvt_kernel<<<dim3(CDIM / 64, HDIM / 64, 8), 256, 0, stream>>>(
        W3, W3, w3t, w3t, HDIM, CDIM, 8);
    transpose_cvt_kernel<<<dim3(HSDIM / 64, CDIM / 64, 2), 256, 0, stream>>>(
        Ws1, Ws2, ws1t, ws2t, CDIM, HSDIM, 1);
    transpose_cvt_kernel<<<dim3(CDIM / 64, HSDIM / 64, 1), 256, 0, stream>>>(
        Ws3, Ws3, ws3t, ws3t, HSDIM, CDIM, 1);

    hipMemsetAsync(meta, 0, 256, stream);
    router_kernel<<<NTOK, 64, 0, stream>>>(x, Wg, idxK, probK, meta);
    offsets_kernel<<<1, 1, 0, stream>>>(meta);
    fill_kernel<<<NTOK / 256, 256, 0, stream>>>(idxK, probK, meta, rowT, rowW, tokSlot);

    gemm12_kernel<<<3520 + 2816, 256, 0, stream>>>(
        xb, w1t, w2t, ws1t, ws2t, hE, hS, rowT, meta);
    gemm3_kernel<<<1280 + 512, 256, 0, stream>>>(
        hE, hS, w3t, ws3t, out, pE, rowT, rowW, meta);
    combine_kernel<<<NTOK, 256, 0, stream>>>(out, pE, tokSlot, rowW);
}